// Round 1
// baseline (102.060 us; speedup 1.0000x reference)
//
#include <hip/hip_runtime.h>
#include <hip/hip_bf16.h>

// Shapes fixed by reference setup_inputs():
//   b=512, N=50, p=32, T=AT=4000, NN=2500
// Output: Z[512,50] then F[2500]  (28100 f32)
//
// f[t,i,j] = softmax_j(-alpha_t * F[i,j]) recomputed on the fly (alpha>0 so
// row-max = -alpha*min_j F). Lane owns row i: d[j]=Fmin-F[i,j] in registers;
// a[pp][:] arrives as wave-uniform ds_read_b128 broadcasts. No f tensor, no
// LDS atomics. Inner loop trimmed to exactly 50 elems; fast rcp for /den.
//
// This revision: (1) alpha pre-scaled by log2(e) at stage time so the inner
// exp is a bare v_exp_f32 (exp2f), removing one v_mul per element;
// (2) den/num accumulation and the al2*d multiply run as packed f32 pairs
// (v_pk_mul/add/fma_f32) — VALU issue drops ~8->3 cyc/elem so the
// quarter-rate trans pipe (v_exp, 8 cyc/wave-elem) becomes the sole limiter.

#define NB   512
#define NN   50
#define NP   32
#define NNN  2500
#define FSTR 52     // LDS row stride (floats): 13*16 B, odd multiple of 16 B

typedef float f32x2 __attribute__((ext_vector_type(2)));

// ---------------- Kernel 1: F[k] = sum_m g[k,m] * w[m]^2 ----------------
__global__ void __launch_bounds__(256) k_F(const float* __restrict__ g,
                                           const float* __restrict__ w,
                                           float* __restrict__ F) {
    const int k = blockIdx.x;
    const float4* __restrict__ row4 = (const float4*)(g + (size_t)k * NNN);
    const float4* __restrict__ w4   = (const float4*)w;
    float s = 0.f;
    for (int m = threadIdx.x; m < NNN / 4; m += 256) {   // 625 float4 per row
        float4 gv = row4[m];
        float4 wv = w4[m];
        s += gv.x * (wv.x * wv.x) + gv.y * (wv.y * wv.y)
           + gv.z * (wv.z * wv.z) + gv.w * (wv.w * wv.w);
    }
    #pragma unroll
    for (int off = 32; off; off >>= 1) s += __shfl_down(s, off, 64);
    __shared__ float part[4];
    if ((threadIdx.x & 63) == 0) part[threadIdx.x >> 6] = s;
    __syncthreads();
    if (threadIdx.x == 0) F[k] = part[0] + part[1] + part[2] + part[3];
}

// ---- Kernel 2 (fused): on-the-fly softmax + gathered einsum + p-reduce ----
__global__ void __launch_bounds__(512) k_Z(const float* __restrict__ x,
                                           const int* __restrict__ x_i,
                                           const int* __restrict__ y_i,
                                           const float* __restrict__ mus,
                                           const float* __restrict__ alphas,
                                           const float* __restrict__ F,
                                           float* __restrict__ Z) {
    const int bb   = blockIdx.x;
    const int tid  = threadIdx.x;
    const int wave = tid >> 6;           // 0..7, handles pp = wave*4 + s
    const int lane = tid & 63;           // lane<50 owns output row i=lane

    __shared__ float Fs[NN * FSTR];
    __shared__ float a[NP][FSTR];
    __shared__ float alph[NP];
    __shared__ float zp[8][NN];

    // ---- stage: Fs, a[pp][j] = x[bb,j,pp] - mus[t_pp,j], alphas ----
    for (int idx = tid; idx < NN * FSTR; idx += 512) {
        const int r = idx / FSTR, c = idx - r * FSTR;
        Fs[idx] = (c < NN) ? F[r * NN + c] : 0.f;        // pads unread
    }
    if (tid < NP) {
        const int t = x_i[bb * NP + tid];
        alph[tid] = alphas[t] * 1.44269504088896f;       // fold log2(e) in
    }
    for (int idx = tid; idx < NN * NP; idx += 512) {     // coalesced x read
        const int j  = idx >> 5;
        const int pp = idx & 31;
        const int t  = x_i[bb * NP + pp];                // L1-cached re-read
        a[pp][j] = x[(size_t)bb * (NN * NP) + idx] - mus[(size_t)t * NN + j];
    }
    __syncthreads();

    // ---- per-lane row into registers: d2[j] = Fmin - F[i,j], 50 exact ----
    const int row = (lane < NN) ? lane : 0;
    const float4* __restrict__ frow4 = (const float4*)(Fs + row * FSTR);
    float4 rv[12];
    #pragma unroll
    for (int k = 0; k < 12; ++k) rv[k] = frow4[k];
    const float2 rt = ((const float2*)frow4)[24];        // elems 48,49
    float mn = fminf(rt.x, rt.y);
    #pragma unroll
    for (int k = 0; k < 12; ++k)
        mn = fminf(mn, fminf(fminf(rv[k].x, rv[k].y), fminf(rv[k].z, rv[k].w)));
    f32x2 d2[25];                                        // 25 packed pairs
    #pragma unroll
    for (int k = 0; k < 12; ++k) {
        f32x2 lo; lo.x = mn - rv[k].x; lo.y = mn - rv[k].y;
        f32x2 hi; hi.x = mn - rv[k].z; hi.y = mn - rv[k].w;
        d2[2 * k]     = lo;
        d2[2 * k + 1] = hi;
    }
    { f32x2 tl; tl.x = mn - rt.x; tl.y = mn - rt.y; d2[24] = tl; }

    // ---- main: 4 pp per wave; a-row via wave-uniform b128 broadcast ----
    float zacc = 0.f;
    #pragma unroll 1
    for (int s = 0; s < 4; ++s) {
        const int pp = (wave << 2) + s;
        const float al2 = alph[pp];
        f32x2 al2v; al2v.x = al2; al2v.y = al2;
        const float4* __restrict__ arow4 = (const float4*)(a[pp]);
        f32x2 num2 = {0.f, 0.f};
        f32x2 den2 = {0.f, 0.f};
        #pragma unroll
        for (int k = 0; k < 12; ++k) {
            const float4 av = arow4[k];
            f32x2 t0 = al2v * d2[2 * k];        // v_pk_mul_f32
            f32x2 t1 = al2v * d2[2 * k + 1];
            f32x2 e0; e0.x = exp2f(t0.x); e0.y = exp2f(t0.y);   // v_exp_f32
            f32x2 e1; e1.x = exp2f(t1.x); e1.y = exp2f(t1.y);
            den2 += e0;                          // v_pk_add_f32
            den2 += e1;
            f32x2 a01; a01.x = av.x; a01.y = av.y;
            f32x2 a23; a23.x = av.z; a23.y = av.w;
            num2 = __builtin_elementwise_fma(e0, a01, num2);    // v_pk_fma_f32
            num2 = __builtin_elementwise_fma(e1, a23, num2);
        }
        const float2 at = ((const float2*)arow4)[24];
        f32x2 tt = al2v * d2[24];
        f32x2 et; et.x = exp2f(tt.x); et.y = exp2f(tt.y);
        den2 += et;
        f32x2 atl; atl.x = at.x; atl.y = at.y;
        num2 = __builtin_elementwise_fma(et, atl, num2);
        const float num = num2.x + num2.y;
        const float den = den2.x + den2.y;
        zacc = fmaf(num, __builtin_amdgcn_rcpf(den), zacc);   // den >= 1
    }
    if (lane < NN) zp[wave][lane] = zacc;
    __syncthreads();

    if (tid < NN) {
        float z = zp[0][tid] + zp[1][tid] + zp[2][tid] + zp[3][tid]
                + zp[4][tid] + zp[5][tid] + zp[6][tid] + zp[7][tid];
        Z[bb * NN + tid] = z + 32.f * mus[(size_t)y_i[bb] * NN + tid];
    }
}

extern "C" void kernel_launch(void* const* d_in, const int* in_sizes, int n_in,
                              void* d_out, int out_size, void* d_ws, size_t ws_size,
                              hipStream_t stream) {
    const float* x      = (const float*)d_in[0];
    const int*   x_i    = (const int*)  d_in[1];
    const int*   y_i    = (const int*)  d_in[2];
    const float* g      = (const float*)d_in[3];
    const float* w      = (const float*)d_in[4];
    const float* mus    = (const float*)d_in[5];
    const float* alphas = (const float*)d_in[6];

    float* Z = (float*)d_out;              // [512*50]
    float* F = Z + NB * NN;                // [2500] (second output)

    k_F<<<NNN, 256, 0, stream>>>(g, w, F);
    k_Z<<<NB,  512, 0, stream>>>(x, x_i, y_i, mus, alphas, F, Z);
}

// Round 2
// 99.028 us; speedup vs baseline: 1.0306x; 1.0306x over previous
//
#include <hip/hip_runtime.h>
#include <hip/hip_bf16.h>

// Shapes fixed by reference setup_inputs():
//   b=512, N=50, p=32, T=AT=4000, NN=2500
// Output: Z[512,50] then F[2500]  (28100 f32)
//
// f[t,i,j] = softmax_j(-alpha_t * F[i,j]) recomputed on the fly (alpha>0 so
// row-max = -alpha*min_j F). Lane owns row i: d[j]=Fmin-F[i,j] in registers;
// a[pp][:] arrives as wave-uniform ds_read_b128 broadcasts. No f tensor, no
// LDS atomics. Inner loop trimmed to exactly 50 elems; fast rcp for /den.
//
// R1 post-mortem: packed-f32 + exp2-prescale was neutral-to-negative (trans
// pipe v_exp is the saturated pipe; 16 waves/CU already overlap VALU with
// trans across waves) and cost 64x absmax. Reverted to the round-0 form.

#define NB   512
#define NN   50
#define NP   32
#define NNN  2500
#define FSTR 52     // LDS row stride (floats): 13*16 B, odd multiple of 16 B

// ---------------- Kernel 1: F[k] = sum_m g[k,m] * w[m]^2 ----------------
__global__ void __launch_bounds__(256) k_F(const float* __restrict__ g,
                                           const float* __restrict__ w,
                                           float* __restrict__ F) {
    const int k = blockIdx.x;
    const float4* __restrict__ row4 = (const float4*)(g + (size_t)k * NNN);
    const float4* __restrict__ w4   = (const float4*)w;
    float s = 0.f;
    for (int m = threadIdx.x; m < NNN / 4; m += 256) {   // 625 float4 per row
        float4 gv = row4[m];
        float4 wv = w4[m];
        s += gv.x * (wv.x * wv.x) + gv.y * (wv.y * wv.y)
           + gv.z * (wv.z * wv.z) + gv.w * (wv.w * wv.w);
    }
    #pragma unroll
    for (int off = 32; off; off >>= 1) s += __shfl_down(s, off, 64);
    __shared__ float part[4];
    if ((threadIdx.x & 63) == 0) part[threadIdx.x >> 6] = s;
    __syncthreads();
    if (threadIdx.x == 0) F[k] = part[0] + part[1] + part[2] + part[3];
}

// ---- Kernel 2 (fused): on-the-fly softmax + gathered einsum + p-reduce ----
__global__ void __launch_bounds__(512) k_Z(const float* __restrict__ x,
                                           const int* __restrict__ x_i,
                                           const int* __restrict__ y_i,
                                           const float* __restrict__ mus,
                                           const float* __restrict__ alphas,
                                           const float* __restrict__ F,
                                           float* __restrict__ Z) {
    const int bb   = blockIdx.x;
    const int tid  = threadIdx.x;
    const int wave = tid >> 6;           // 0..7, handles pp = wave*4 + s
    const int lane = tid & 63;           // lane<50 owns output row i=lane

    __shared__ float Fs[NN * FSTR];
    __shared__ float a[NP][FSTR];
    __shared__ float alph[NP];
    __shared__ float zp[8][NN];

    // ---- stage: Fs, a[pp][j] = x[bb,j,pp] - mus[t_pp,j], alphas ----
    for (int idx = tid; idx < NN * FSTR; idx += 512) {
        const int r = idx / FSTR, c = idx - r * FSTR;
        Fs[idx] = (c < NN) ? F[r * NN + c] : 0.f;        // pads unread
    }
    if (tid < NP) {
        const int t = x_i[bb * NP + tid];
        alph[tid] = alphas[t];
    }
    for (int idx = tid; idx < NN * NP; idx += 512) {     // coalesced x read
        const int j  = idx >> 5;
        const int pp = idx & 31;
        const int t  = x_i[bb * NP + pp];                // L1-cached re-read
        a[pp][j] = x[(size_t)bb * (NN * NP) + idx] - mus[(size_t)t * NN + j];
    }
    __syncthreads();

    // ---- per-lane row into registers: d[j] = Fmin - F[i,j], 50 exact ----
    const int row = (lane < NN) ? lane : 0;
    const float4* __restrict__ frow4 = (const float4*)(Fs + row * FSTR);
    float4 rv[12];
    #pragma unroll
    for (int k = 0; k < 12; ++k) rv[k] = frow4[k];
    const float2 rt = ((const float2*)frow4)[24];        // elems 48,49
    float mn = fminf(rt.x, rt.y);
    #pragma unroll
    for (int k = 0; k < 12; ++k)
        mn = fminf(mn, fminf(fminf(rv[k].x, rv[k].y), fminf(rv[k].z, rv[k].w)));
    float d[NN];
    #pragma unroll
    for (int k = 0; k < 12; ++k) {
        d[4 * k + 0] = mn - rv[k].x;
        d[4 * k + 1] = mn - rv[k].y;
        d[4 * k + 2] = mn - rv[k].z;
        d[4 * k + 3] = mn - rv[k].w;
    }
    d[48] = mn - rt.x;
    d[49] = mn - rt.y;

    // ---- main: 4 pp per wave; a-row via wave-uniform b128 broadcast ----
    float zacc = 0.f;
    #pragma unroll 1
    for (int s = 0; s < 4; ++s) {
        const int pp = (wave << 2) + s;
        const float al = alph[pp];
        const float4* __restrict__ arow4 = (const float4*)(a[pp]);
        float num = 0.f, den = 0.f;
        #pragma unroll
        for (int k = 0; k < 12; ++k) {
            const float4 av = arow4[k];
            float e0 = __expf(al * d[4 * k + 0]); den += e0; num = fmaf(e0, av.x, num);
            float e1 = __expf(al * d[4 * k + 1]); den += e1; num = fmaf(e1, av.y, num);
            float e2 = __expf(al * d[4 * k + 2]); den += e2; num = fmaf(e2, av.z, num);
            float e3 = __expf(al * d[4 * k + 3]); den += e3; num = fmaf(e3, av.w, num);
        }
        const float2 at = ((const float2*)arow4)[24];
        float e48 = __expf(al * d[48]); den += e48; num = fmaf(e48, at.x, num);
        float e49 = __expf(al * d[49]); den += e49; num = fmaf(e49, at.y, num);
        zacc = fmaf(num, __builtin_amdgcn_rcpf(den), zacc);   // den >= 1
    }
    if (lane < NN) zp[wave][lane] = zacc;
    __syncthreads();

    if (tid < NN) {
        float z = zp[0][tid] + zp[1][tid] + zp[2][tid] + zp[3][tid]
                + zp[4][tid] + zp[5][tid] + zp[6][tid] + zp[7][tid];
        Z[bb * NN + tid] = z + 32.f * mus[(size_t)y_i[bb] * NN + tid];
    }
}

extern "C" void kernel_launch(void* const* d_in, const int* in_sizes, int n_in,
                              void* d_out, int out_size, void* d_ws, size_t ws_size,
                              hipStream_t stream) {
    const float* x      = (const float*)d_in[0];
    const int*   x_i    = (const int*)  d_in[1];
    const int*   y_i    = (const int*)  d_in[2];
    const float* g      = (const float*)d_in[3];
    const float* w      = (const float*)d_in[4];
    const float* mus    = (const float*)d_in[5];
    const float* alphas = (const float*)d_in[6];

    float* Z = (float*)d_out;              // [512*50]
    float* F = Z + NB * NN;                // [2500] (second output)

    k_F<<<NNN, 256, 0, stream>>>(g, w, F);
    k_Z<<<NB,  512, 0, stream>>>(x, x_i, y_i, mus, alphas, F, Z);
}